// Round 4
// baseline (14.270 us; speedup 1.0000x reference)
//
#include <hip/hip_runtime.h>

// DirectionalConv2D: 5x5 wind-directional Gaussian blur, f32. B=4, H=W=512.
// w_ij = A^{ai^2} * B^{aj^2} * g^{ai*aj}; A=exp(-I c^2), B=exp(-I s^2), g=exp(-2 I c s)
// I = 1/(2*sigma^2) = 1/4.5; c,s = normalized (u+1e-8, v). B = exp(-I)/A.
// R4: 2 px/thread (float2 windows) -> 8192 waves -> 8 waves/SIMD for latency hiding.
// All loads branch-free (clamped addr + 0/1 masks), issued up front.

constexpr int Wd = 512;
constexpr int Hd = 512;

__global__ __launch_bounds__(256, 8) void dirconv_kernel(
    const float* __restrict__ fire,
    const float* __restrict__ wu,
    const float* __restrict__ wv,
    float* __restrict__ out,
    int total)
{
    constexpr float C1 = -0.3205988979753274f;   // -log2(e)/4.5
    constexpr float C2 = -0.6411977959506548f;   // -2*log2(e)/4.5
    constexpr float KB = 0.8007374029168082f;    // exp(-1/4.5)

    int t = blockIdx.x * 256 + threadIdx.x;
    int p = t << 1;                      // 2 consecutive x-pixels per thread
    if (p >= total) return;

    int rem = p & (Hd * Wd - 1);
    int y = rem >> 9;
    int x = rem & (Wd - 1);              // even
    const float* img = fire + (p - rem);

    // ---- loads first: u/v (coeff deps), then 15 row float2 loads ----
    float2 u2 = *reinterpret_cast<const float2*>(wu + p);
    float2 v2 = *reinterpret_cast<const float2*>(wv + p);

    int xm = (x >= 2) ? x - 2 : 0;             // clamped left float2
    int xp = (x + 3 < Wd) ? x + 2 : Wd - 4;    // clamped right float2
    float lmask = (x >= 2) ? 1.0f : 0.0f;
    float rmask = (x + 3 < Wd) ? 1.0f : 0.0f;

    float2 Lr[5], Mr[5], Rr[5];
    float rvm[5];
#pragma unroll
    for (int di = 0; di < 5; ++di) {
        int row = y + di - 2;
        rvm[di] = ((unsigned)row < (unsigned)Hd) ? 1.0f : 0.0f;
        int rc = min(max(row, 0), Hd - 1);
        const float* rp = img + (rc << 9);
        Lr[di] = *reinterpret_cast<const float2*>(rp + xm);
        Mr[di] = *reinterpret_cast<const float2*>(rp + x);
        Rr[di] = *reinterpret_cast<const float2*>(rp + xp);
    }

    // ---- per-pixel coefficients (waits only on u2/v2; row loads in flight) ----
    float ua[2] = {u2.x, u2.y};
    float va[2] = {v2.x, v2.y};

    float A1[2], A4[2], B1a[2], B4a[2], WsA[2], S[2];
    float c1[2], c2[2], c3[2], c4[2], d1[2], d2[2], d3[2], d4[2];

#pragma unroll
    for (int k = 0; k < 2; ++k) {
        float un = ua[k] + 1e-8f;
        float vv = va[k];
        float r2 = fmaf(un, un, vv * vv);
        r2 = fmaxf(r2, 1e-36f);
        float ir = __builtin_amdgcn_rsqf(r2);
        float c = un * ir;
        float s = vv * ir;
        float a1 = exp2f(c * c * C1);              // A = exp(-I c^2)
        float g  = exp2f(c * s * C2);              // g = exp(-2 I c s)
        float b1 = KB * __builtin_amdgcn_rcpf(a1); // B = exp(-I)/A
        float a2 = a1 * a1;  float A4v = a2 * a2;
        float b2 = b1 * b1;  float B4v = b2 * b2;
        float gi  = __builtin_amdgcn_rcpf(g);
        float g2 = g * g,   gi2 = gi * gi;
        float g4 = g2 * g2, gi4 = gi2 * gi2;
        c1[k] = b1 * g;  c2[k] = b1 * gi;  c3[k] = B4v * g2;  c4[k] = B4v * gi2;
        d1[k] = b1 * g2; d2[k] = b1 * gi2; d3[k] = B4v * g4;  d4[k] = B4v * gi4;
        A1[k] = a1; A4[k] = A4v; B1a[k] = b1; B4a[k] = B4v;
        float sc = 1.0f + ((c1[k] + c2[k]) + (c3[k] + c4[k]));
        float sd = 1.0f + ((d1[k] + d2[k]) + (d3[k] + d4[k]));
        float base = fmaf(2.0f, b1 + B4v, 1.0f);
        WsA[k] = fmaf(2.0f, fmaf(a1, sc, A4v * sd), base);
        S[k] = 0.0f;
    }

    // ---- accumulate rows (fully unrolled) ----
#pragma unroll
    for (int di = 0; di < 5; ++di) {
        const int ai = di - 2;
        // window cols x-2..x+3 -> fv[0..5]; boundary pairs masked to 0
        float fv[6] = {Lr[di].x * lmask, Lr[di].y * lmask,
                       Mr[di].x,         Mr[di].y,
                       Rr[di].x * rmask, Rr[di].y * rmask};
#pragma unroll
        for (int k = 0; k < 2; ++k) {
            float fm2 = fv[k], fm1 = fv[k + 1], f0 = fv[k + 2];
            float fp1 = fv[k + 3], fp2 = fv[k + 4];
            if (ai == 0) {
                float R = fmaf(B4a[k], fm2 + fp2, fmaf(B1a[k], fm1 + fp1, f0));
                S[k] += R;   // center row always valid
            } else if (ai == 1) {
                float R = fmaf(c4[k], fm2, fmaf(c2[k], fm1,
                          fmaf(c1[k], fp1, fmaf(c3[k], fp2, f0))));
                S[k] = fmaf(A1[k] * rvm[di], R, S[k]);
            } else if (ai == -1) {
                float R = fmaf(c3[k], fm2, fmaf(c1[k], fm1,
                          fmaf(c2[k], fp1, fmaf(c4[k], fp2, f0))));
                S[k] = fmaf(A1[k] * rvm[di], R, S[k]);
            } else if (ai == 2) {
                float R = fmaf(d4[k], fm2, fmaf(d2[k], fm1,
                          fmaf(d1[k], fp1, fmaf(d3[k], fp2, f0))));
                S[k] = fmaf(A4[k] * rvm[di], R, S[k]);
            } else { // ai == -2
                float R = fmaf(d3[k], fm2, fmaf(d1[k], fm1,
                          fmaf(d2[k], fp1, fmaf(d4[k], fp2, f0))));
                S[k] = fmaf(A4[k] * rvm[di], R, S[k]);
            }
        }
    }

    float2 o;
#pragma unroll
    for (int k = 0; k < 2; ++k) {
        float inv = __builtin_amdgcn_rcpf(WsA[k] + 1e-8f);
        float sp = S[k] * inv;
        float fcenter = (k == 0) ? Mr[2].x : Mr[2].y;   // fire at center
        float r = fmaf(0.7f, sp, 0.3f * fcenter);
        r = fminf(fmaxf(r, 0.0f), 1.0f);
        (&o.x)[k] = r;
    }
    *reinterpret_cast<float2*>(out + p) = o;
}

extern "C" void kernel_launch(void* const* d_in, const int* in_sizes, int n_in,
                              void* d_out, int out_size, void* d_ws, size_t ws_size,
                              hipStream_t stream) {
    const float* fire = (const float*)d_in[0];
    const float* wu   = (const float*)d_in[1];
    const float* wv   = (const float*)d_in[2];
    float* out        = (float*)d_out;
    int total = out_size;                     // B*H*W = 1048576
    int threads = (total + 1) / 2;
    int blocks = (threads + 255) / 256;       // 2048 blocks -> 8 blocks/CU
    dirconv_kernel<<<blocks, 256, 0, stream>>>(fire, wu, wv, out, total);
}

// Round 5
// 10.066 us; speedup vs baseline: 1.4177x; 1.4177x over previous
//
#include <hip/hip_runtime.h>

// DirectionalConv2D: 5x5 wind-directional Gaussian blur, f32. B=4, H=W=512.
// w_ij = A^{ai^2} * B^{aj^2} * g^{ai*aj}; A=exp(-I c^2), B=exp(-I s^2), g=exp(-2 I c s)
// I = 1/(2*sigma^2) = 1/4.5; c,s = normalized (u+1e-8, v). B = exp(-I)/A.
// R5: cooperative LDS staging. One block = one image row-pair (1024 px, 4px/thread).
// Stage 6 halo rows into LDS (zero side-pads + zero OOB rows) -> 6 VMEM/thread
// (vs 19), no boundary masks anywhere. Analytic 25-tap weight sum unchanged.

constexpr int Wd = 512;
constexpr int Hd = 512;
constexpr int PW = 520;   // 4 pad + 512 + 4 pad

__global__ __launch_bounds__(256, 4) void dirconv_kernel(
    const float* __restrict__ fire,
    const float* __restrict__ wu,
    const float* __restrict__ wv,
    float* __restrict__ out)
{
    constexpr float C1 = -0.3205988979753274f;   // -log2(e)/4.5
    constexpr float C2 = -0.6411977959506548f;   // -2*log2(e)/4.5
    constexpr float KB = 0.8007374029168082f;    // exp(-1/4.5)

    __shared__ float lds[6][PW];                 // 12,480 B

    const int blk = blockIdx.x;                  // 0..1023
    const int b  = blk >> 8;                     // image index
    const int y0 = (blk & 255) << 1;             // first of the 2 output rows
    const int t  = threadIdx.x;
    const float* img = fire + (b << 18);         // 512*512 per image

    // per-pixel coords: threads 0-127 -> row y0, 128-255 -> row y0+1
    const int lrow = t >> 7;                     // 0 or 1
    const int x = (t & 127) << 2;                // multiple of 4
    const int p = (b << 18) + ((y0 + lrow) << 9) + x;

    // ---- issue per-pixel u,v loads first (coeff deps) ----
    float4 u4 = *reinterpret_cast<const float4*>(wu + p);
    float4 v4 = *reinterpret_cast<const float4*>(wv + p);

    // ---- zero the side pads (cols 0-3 and 516-519 of each LDS row) ----
    if (t < 12) {
        int r = t >> 1, sd = t & 1;
        *reinterpret_cast<float4*>(&lds[r][sd ? 516 : 0]) =
            make_float4(0.f, 0.f, 0.f, 0.f);
    }
    // ---- cooperative stage: 6 rows x 128 float4 = 768 tasks, 3/thread ----
#pragma unroll
    for (int j = 0; j < 3; ++j) {
        int id = t + (j << 8);                   // 0..767
        int r  = id >> 7;                        // staged row 0..5
        int q  = id & 127;                       // float4 index within row
        int gr = y0 - 2 + r;                     // global image row
        float4 val = make_float4(0.f, 0.f, 0.f, 0.f);
        if ((unsigned)gr < (unsigned)Hd)         // wave-uniform branch
            val = *reinterpret_cast<const float4*>(img + (gr << 9) + (q << 2));
        *reinterpret_cast<float4*>(&lds[r][4 + (q << 2)]) = val;
    }

    // ---- per-pixel coefficients (overlaps staging loads in flight) ----
    float ua[4] = {u4.x, u4.y, u4.z, u4.w};
    float va[4] = {v4.x, v4.y, v4.z, v4.w};

    float A1[4], A4[4], B1a[4], B4a[4], WsA[4], S[4];
    float c1[4], c2[4], c3[4], c4[4], d1[4], d2[4], d3[4], d4[4];

#pragma unroll
    for (int k = 0; k < 4; ++k) {
        float un = ua[k] + 1e-8f;
        float vv = va[k];
        float r2 = fmaf(un, un, vv * vv);
        r2 = fmaxf(r2, 1e-36f);
        float ir = __builtin_amdgcn_rsqf(r2);
        float c = un * ir;
        float s = vv * ir;
        float a1 = exp2f(c * c * C1);              // A = exp(-I c^2)
        float g  = exp2f(c * s * C2);              // g = exp(-2 I c s)
        float b1 = KB * __builtin_amdgcn_rcpf(a1); // B = exp(-I)/A
        float a2 = a1 * a1;  float A4v = a2 * a2;
        float b2 = b1 * b1;  float B4v = b2 * b2;
        float gi  = __builtin_amdgcn_rcpf(g);
        float g2 = g * g,   gi2 = gi * gi;
        float g4 = g2 * g2, gi4 = gi2 * gi2;
        c1[k] = b1 * g;  c2[k] = b1 * gi;  c3[k] = B4v * g2;  c4[k] = B4v * gi2;
        d1[k] = b1 * g2; d2[k] = b1 * gi2; d3[k] = B4v * g4;  d4[k] = B4v * gi4;
        A1[k] = a1; A4[k] = A4v; B1a[k] = b1; B4a[k] = B4v;
        float sc = 1.0f + ((c1[k] + c2[k]) + (c3[k] + c4[k]));
        float sd = 1.0f + ((d1[k] + d2[k]) + (d3[k] + d4[k]));
        float base = fmaf(2.0f, b1 + B4v, 1.0f);
        WsA[k] = fmaf(2.0f, fmaf(a1, sc, A4v * sd), base);
        S[k] = 0.0f;
    }

    __syncthreads();

    // ---- accumulate 5 window rows from LDS (no masks: pads/OOB are zeros) ----
    float4 fcen = make_float4(0.f, 0.f, 0.f, 0.f);   // fire at center (residual)
#pragma unroll
    for (int di = 0; di < 5; ++di) {
        const int ai = di - 2;
        const int r = lrow + di;
        // lds col c holds global col c-4; need global x-2..x+5 -> lds x+2..x+9
        float4 L = *reinterpret_cast<const float4*>(&lds[r][x]);
        float4 M = *reinterpret_cast<const float4*>(&lds[r][x + 4]);
        float4 R4v = *reinterpret_cast<const float4*>(&lds[r][x + 8]);
        if (di == 2) fcen = M;                       // global cols x..x+3
        float fv[8] = {L.z, L.w, M.x, M.y, M.z, M.w, R4v.x, R4v.y};
#pragma unroll
        for (int k = 0; k < 4; ++k) {
            float fm2 = fv[k], fm1 = fv[k + 1], f0 = fv[k + 2];
            float fp1 = fv[k + 3], fp2 = fv[k + 4];
            if (ai == 0) {
                float R = fmaf(B4a[k], fm2 + fp2, fmaf(B1a[k], fm1 + fp1, f0));
                S[k] += R;
            } else if (ai == 1) {
                float R = fmaf(c4[k], fm2, fmaf(c2[k], fm1,
                          fmaf(c1[k], fp1, fmaf(c3[k], fp2, f0))));
                S[k] = fmaf(A1[k], R, S[k]);
            } else if (ai == -1) {
                float R = fmaf(c3[k], fm2, fmaf(c1[k], fm1,
                          fmaf(c2[k], fp1, fmaf(c4[k], fp2, f0))));
                S[k] = fmaf(A1[k], R, S[k]);
            } else if (ai == 2) {
                float R = fmaf(d4[k], fm2, fmaf(d2[k], fm1,
                          fmaf(d1[k], fp1, fmaf(d3[k], fp2, f0))));
                S[k] = fmaf(A4[k], R, S[k]);
            } else { // ai == -2
                float R = fmaf(d3[k], fm2, fmaf(d1[k], fm1,
                          fmaf(d2[k], fp1, fmaf(d4[k], fp2, f0))));
                S[k] = fmaf(A4[k], R, S[k]);
            }
        }
    }

    float fcena[4] = {fcen.x, fcen.y, fcen.z, fcen.w};
    float4 o;
#pragma unroll
    for (int k = 0; k < 4; ++k) {
        float inv = __builtin_amdgcn_rcpf(WsA[k] + 1e-8f);
        float sp = S[k] * inv;
        float r = fmaf(0.7f, sp, 0.3f * fcena[k]);
        r = fminf(fmaxf(r, 0.0f), 1.0f);
        (&o.x)[k] = r;
    }
    *reinterpret_cast<float4*>(out + p) = o;
}

extern "C" void kernel_launch(void* const* d_in, const int* in_sizes, int n_in,
                              void* d_out, int out_size, void* d_ws, size_t ws_size,
                              hipStream_t stream) {
    const float* fire = (const float*)d_in[0];
    const float* wu   = (const float*)d_in[1];
    const float* wv   = (const float*)d_in[2];
    float* out        = (float*)d_out;
    // B*H*W = 1048576 px; 1024 px per block (one row-pair), 4 px/thread
    int blocks = out_size >> 10;              // 1024
    dirconv_kernel<<<blocks, 256, 0, stream>>>(fire, wu, wv, out);
}